// Round 5
// baseline (445.589 us; speedup 1.0000x reference)
//
#include <hip/hip_runtime.h>

#define N_ROWS    65536
#define N_CLASSES 1000
#define N_QUADS   250          // 1000 f32 = 250 float4 per row
#define GRID      2048         // x4 waves = 8192 waves; 8 contiguous rows/wave

typedef float v4f __attribute__((ext_vector_type(4)));

// d_ws layout: [0 .. 2047]  float partials
//              [2048]       uint32 arrival counter (memset to 0 each launch)
#define CTR_OFF   2048

__global__ __launch_bounds__(256, 2)
void cosine_loss_fused(const float* __restrict__ pred,
                       const int*   __restrict__ tgt,
                       float*       __restrict__ ws,
                       float*       __restrict__ out) {
    const int lane   = threadIdx.x & 63;
    const int wiv    = threadIdx.x >> 6;
    const int waveId = blockIdx.x * 4 + wiv;
    const int base   = waveId * 8;          // 8 contiguous rows per wave

    float acc = 0.0f;   // per-lane; cross-lane summed ONCE at the end

    int t[8];
    v4f v[8][4];        // 32 global_load_dwordx4 in flight per wave

    #pragma unroll
    for (int j = 0; j < 8; ++j) {
        const int row = base + j;
        const v4f* rp = (const v4f*)(pred + (size_t)row * N_CLASSES);
        t[j] = tgt[row];                    // wave-uniform -> scalar load
        // chunks 0..2: lane+128 <= 191 < 250, always in bounds
        v[j][0] = rp[lane];
        v[j][1] = rp[lane + 64];
        v[j][2] = rp[lane + 128];
        v[j][3] = (lane < N_QUADS - 192) ? rp[lane + 192]
                                         : (v4f){0.f, 0.f, 0.f, 0.f};
    }

    float ss[8], g[8];
    #pragma unroll
    for (int j = 0; j < 8; ++j) {
        const int tq = t[j] >> 2, tr = t[j] & 3;
        ss[j] = 0.f; g[j] = 0.f;
        #pragma unroll
        for (int i = 0; i < 4; ++i) {
            const int idx = lane + 64 * i;
            const v4f w = v[j][i];
            ss[j] += w.x * w.x + w.y * w.y + w.z * w.z + w.w * w.w;
            if (idx == tq)
                g[j] = (tr == 0) ? w.x : (tr == 1) ? w.y : (tr == 2) ? w.z : w.w;
        }
    }

    // 8 independent butterfly chains (ss only) — interleaved, latency overlaps.
    #pragma unroll
    for (int off = 32; off > 0; off >>= 1) {
        #pragma unroll
        for (int j = 0; j < 8; ++j)
            ss[j] += __shfl_xor(ss[j], off, 64);
    }

    #pragma unroll
    for (int j = 0; j < 8; ++j) {
        const float norm = __builtin_amdgcn_sqrtf(ss[j]);
        acc -= g[j] * __builtin_amdgcn_rcpf(norm + 1e-9f);
        if (lane == 0) {
            const float d = 1.0f - norm;
            acc += 0.1f * d * d;
        }
    }

    // One cross-lane reduction per wave.
    #pragma unroll
    for (int off = 32; off > 0; off >>= 1)
        acc += __shfl_xor(acc, off, 64);

    __shared__ float smem[4];
    __shared__ int   is_last;
    if (lane == 0) smem[wiv] = acc;
    __syncthreads();

    if (threadIdx.x == 0) {
        const float partial = smem[0] + smem[1] + smem[2] + smem[3];
        // Device-scope release store of our partial, then arrival tick.
        __hip_atomic_store(&ws[blockIdx.x], partial,
                           __ATOMIC_RELAXED, __HIP_MEMORY_SCOPE_AGENT);
        unsigned* ctr = (unsigned*)&ws[CTR_OFF];
        const unsigned old = __hip_atomic_fetch_add(ctr, 1u,
                               __ATOMIC_ACQ_REL, __HIP_MEMORY_SCOPE_AGENT);
        is_last = (old == GRID - 1) ? 1 : 0;
    }
    __syncthreads();

    if (is_last) {
        // Last block: reduce all 2048 partials (8 per thread, agent-scope loads
        // so per-XCD L2s can't serve stale lines).
        float s = 0.f;
        #pragma unroll
        for (int k = 0; k < GRID / 256; ++k)
            s += __hip_atomic_load(&ws[threadIdx.x + 256 * k],
                                   __ATOMIC_RELAXED, __HIP_MEMORY_SCOPE_AGENT);
        #pragma unroll
        for (int off = 32; off > 0; off >>= 1)
            s += __shfl_xor(s, off, 64);
        __shared__ float fsm[4];
        if (lane == 0) fsm[wiv] = s;
        __syncthreads();
        if (threadIdx.x == 0)
            out[0] = (fsm[0] + fsm[1] + fsm[2] + fsm[3]) * (1.0f / (float)N_ROWS);
    }
}

extern "C" void kernel_launch(void* const* d_in, const int* in_sizes, int n_in,
                              void* d_out, int out_size, void* d_ws, size_t ws_size,
                              hipStream_t stream) {
    const float* pred = (const float*)d_in[0];
    const int*   tgt  = (const int*)d_in[1];
    float*       out  = (float*)d_out;
    float*       ws   = (float*)d_ws;

    // Zero the arrival counter (4 bytes) — graph-capturable memset node.
    hipMemsetAsync((char*)d_ws + CTR_OFF * sizeof(float), 0, sizeof(unsigned),
                   stream);
    cosine_loss_fused<<<GRID, 256, 0, stream>>>(pred, tgt, ws, out);
}

// Round 6
// 324.404 us; speedup vs baseline: 1.3736x; 1.3736x over previous
//
#include <hip/hip_runtime.h>

#define N_ROWS    65536
#define N_CLASSES 1000
#define N_QUADS   250          // 1000 f32 = 250 float4 per row
#define GRID      2048
#define WAVES_TOT (GRID * 4)   // 8192 waves, 8 rows/wave, 2 iterations of 4 rows

typedef float v4f __attribute__((ext_vector_type(4)));

__global__ __launch_bounds__(256, 4)
void cosine_loss_main(const float* __restrict__ pred,
                      const int*   __restrict__ tgt,
                      float*       __restrict__ partials) {
    const int lane   = threadIdx.x & 63;
    const int wiv    = threadIdx.x >> 6;
    const int waveId = blockIdx.x * 4 + wiv;

    float acc = 0.0f;   // per-lane; cross-lane summed ONCE at the end

    // N_ROWS == 8 * WAVES_TOT, so exactly 2 full iterations of 4 rows/wave.
    #pragma unroll 1
    for (int r = waveId; r < N_ROWS; r += 4 * WAVES_TOT) {
        int  t[4];
        v4f  v[4][4];            // [row][quad] — 16 dwordx4 loads in flight

        #pragma unroll
        for (int j = 0; j < 4; ++j) {
            const int row = r + j * WAVES_TOT;
            const v4f* rp = (const v4f*)(pred + (size_t)row * N_CLASSES);
            t[j] = tgt[row];     // wave-uniform -> scalar load
            // chunks 0..2: lane+128 <= 191 < 250, always in bounds
            v[j][0] = __builtin_nontemporal_load(&rp[lane]);
            v[j][1] = __builtin_nontemporal_load(&rp[lane + 64]);
            v[j][2] = __builtin_nontemporal_load(&rp[lane + 128]);
            v[j][3] = (lane < N_QUADS - 192)
                        ? __builtin_nontemporal_load(&rp[lane + 192])
                        : (v4f){0.f, 0.f, 0.f, 0.f};
        }

        float ss[4], g[4];
        #pragma unroll
        for (int j = 0; j < 4; ++j) {
            const int tq = t[j] >> 2, tr = t[j] & 3;
            ss[j] = 0.f; g[j] = 0.f;
            #pragma unroll
            for (int i = 0; i < 4; ++i) {
                const int idx = lane + 64 * i;
                const v4f w = v[j][i];
                ss[j] += w.x * w.x + w.y * w.y + w.z * w.z + w.w * w.w;
                if (idx == tq)
                    g[j] = (tr == 0) ? w.x : (tr == 1) ? w.y : (tr == 2) ? w.z : w.w;
            }
        }

        // 4 independent butterfly chains (ss only) — interleaved, latency overlaps.
        #pragma unroll
        for (int off = 32; off > 0; off >>= 1) {
            #pragma unroll
            for (int j = 0; j < 4; ++j)
                ss[j] += __shfl_xor(ss[j], off, 64);
        }

        #pragma unroll
        for (int j = 0; j < 4; ++j) {
            const float norm = __builtin_amdgcn_sqrtf(ss[j]);
            acc -= g[j] * __builtin_amdgcn_rcpf(norm + 1e-9f);
            if (lane == 0) {
                const float d = 1.0f - norm;
                acc += 0.1f * d * d;
            }
        }
    }

    // One cross-lane reduction per wave.
    #pragma unroll
    for (int off = 32; off > 0; off >>= 1)
        acc += __shfl_xor(acc, off, 64);

    __shared__ float smem[4];
    if (lane == 0) smem[wiv] = acc;
    __syncthreads();
    if (threadIdx.x == 0)
        partials[blockIdx.x] = smem[0] + smem[1] + smem[2] + smem[3];
}

__global__ __launch_bounds__(256)
void cosine_loss_finish(const float* __restrict__ partials,
                        float*       __restrict__ out) {
    const int lane = threadIdx.x & 63;
    const int wiv  = threadIdx.x >> 6;
    float s = 0.f;
    #pragma unroll
    for (int k = 0; k < GRID / 256; ++k)
        s += partials[threadIdx.x + 256 * k];
    #pragma unroll
    for (int off = 32; off > 0; off >>= 1)
        s += __shfl_xor(s, off, 64);
    __shared__ float smem[4];
    if (lane == 0) smem[wiv] = s;
    __syncthreads();
    if (threadIdx.x == 0)
        out[0] = (smem[0] + smem[1] + smem[2] + smem[3]) * (1.0f / (float)N_ROWS);
}

extern "C" void kernel_launch(void* const* d_in, const int* in_sizes, int n_in,
                              void* d_out, int out_size, void* d_ws, size_t ws_size,
                              hipStream_t stream) {
    const float* pred = (const float*)d_in[0];
    const int*   tgt  = (const int*)d_in[1];
    float*       out  = (float*)d_out;
    float*       partials = (float*)d_ws;   // 2048 floats = 8 KB scratch

    cosine_loss_main<<<GRID, 256, 0, stream>>>(pred, tgt, partials);
    cosine_loss_finish<<<1, 256, 0, stream>>>(partials, out);
}